// Round 5
// baseline (134.675 us; speedup 1.0000x reference)
//
#include <hip/hip_runtime.h>
#include <hip/hip_bf16.h>
#include <math.h>

// Shapes: x(8,64,128,128) f32; wt(4,4,64,64,3,3) f32; attn_w(4,64); attn_b(4)
// Subband space: 64x64, 4 subbands, 64 cin, 64 cout.

typedef __bf16 bf16x8 __attribute__((ext_vector_type(8)));
typedef float f32x4 __attribute__((ext_vector_type(4)));

__device__ __forceinline__ bf16x8 as_bf16x8(uint4 u) {
    union { uint4 a; bf16x8 b; } c; c.a = u; return c.b;
}
__device__ __forceinline__ unsigned short bf16bits(float f) {
    __hip_bfloat16 h = __float2bfloat16(f);
    union { __hip_bfloat16 h; unsigned short u; } c; c.h = h; return c.u;
}

// ---------------------------------------------------------------------------
// K1: Haar DWT -> bf16 feats[b][sub][y][x][c] + per-y partial logits
//     plog[b][sub][k][y] (no atomics, no zero-init needed).
// grid (64 y, 8 b), 256 threads.
// ---------------------------------------------------------------------------
__global__ __launch_bounds__(256)
void dwt_kernel(const float* __restrict__ x, const float* __restrict__ attn_w,
                unsigned short* __restrict__ feats, float* __restrict__ plog) {
    __shared__ uint4 sT[2304];                     // 4 sub * 64 x * 9 chunks (72 bf16)
    __shared__ float sred[64][4];                  // [c][sub] per-block channel sums
    unsigned short* sTu = (unsigned short*)sT;
    int y = blockIdx.x, b = blockIdx.y;
    int t = threadIdx.x;
    int c = t >> 2, q = t & 3;

    const float4* r0 = (const float4*)x + ((size_t)(b * 64 + c) * 128 + 2 * y) * 32;
    const float4* r1 = r0 + 32;                    // next image row

    float s0 = 0.f, s1 = 0.f, s2 = 0.f, s3 = 0.f;
    #pragma unroll
    for (int i = 0; i < 8; ++i) {
        int f = i * 4 + q;                         // quad covers 4 consecutive float4
        float4 p = r0[f], qq = r1[f];
        int xo = 2 * f;
        {
            float a = p.x, bb = p.y, cc = qq.x, dd = qq.y;
            float ll = (a + bb + cc + dd) * 0.5f, h0 = (a + bb - cc - dd) * 0.5f;
            float h1 = (a - bb + cc - dd) * 0.5f, hh = (a - bb - cc + dd) * 0.5f;
            s0 += ll; s1 += h0; s2 += h1; s3 += hh;
            sTu[0 * 4608 + xo * 72 + c] = bf16bits(ll);
            sTu[1 * 4608 + xo * 72 + c] = bf16bits(h0);
            sTu[2 * 4608 + xo * 72 + c] = bf16bits(h1);
            sTu[3 * 4608 + xo * 72 + c] = bf16bits(hh);
        }
        {
            float a = p.z, bb = p.w, cc = qq.z, dd = qq.w;
            float ll = (a + bb + cc + dd) * 0.5f, h0 = (a + bb - cc - dd) * 0.5f;
            float h1 = (a - bb + cc - dd) * 0.5f, hh = (a - bb - cc + dd) * 0.5f;
            s0 += ll; s1 += h0; s2 += h1; s3 += hh;
            sTu[0 * 4608 + (xo + 1) * 72 + c] = bf16bits(ll);
            sTu[1 * 4608 + (xo + 1) * 72 + c] = bf16bits(h0);
            sTu[2 * 4608 + (xo + 1) * 72 + c] = bf16bits(h1);
            sTu[3 * 4608 + (xo + 1) * 72 + c] = bf16bits(hh);
        }
    }
    // reduce over q (4 consecutive lanes share c) -> sred[c][sub]
    s0 += __shfl_xor(s0, 1); s0 += __shfl_xor(s0, 2);
    s1 += __shfl_xor(s1, 1); s1 += __shfl_xor(s1, 2);
    s2 += __shfl_xor(s2, 1); s2 += __shfl_xor(s2, 2);
    s3 += __shfl_xor(s3, 1); s3 += __shfl_xor(s3, 2);
    if (q == 0) { sred[c][0] = s0; sred[c][1] = s1; sred[c][2] = s2; sred[c][3] = s3; }
    __syncthreads();
    // per-y partial logits (16 threads; others proceed to feats write)
    if (t < 16) {
        int sub = t >> 2, k = t & 3;
        float acc = 0.f;
        #pragma unroll 8
        for (int cc = 0; cc < 64; ++cc)
            acc += attn_w[k * 64 + cc] * sred[cc][sub];
        plog[((size_t)(b * 4 + sub) * 4 + k) * 64 + y] = acc;
    }
    // coalesced channel-last global writes (16B/lane)
    uint4* fch = (uint4*)feats;
    for (int e = t; e < 2048; e += 256) {
        int s = e >> 9, xx = (e >> 3) & 63, ck = e & 7;
        fch[(size_t)((b * 4 + s) * 64 + y) * 512 + xx * 8 + ck] = sT[s * 576 + xx * 9 + ck];
    }
}

// ---------------------------------------------------------------------------
// K2: attention (from plog) + kernel mixing -> bf16 wmix[b][sub][tap][co][ci]
// grid (64 co, 4 sub), 256 threads.
// ---------------------------------------------------------------------------
__global__ __launch_bounds__(256)
void mix_kernel(const float* __restrict__ wt, const float* __restrict__ attn_b,
                const float* __restrict__ plog, unsigned short* __restrict__ wmix) {
    __shared__ float sLw[4][576];       // [k][ci*9+tap]
    __shared__ float satt[8][4];        // [b][k]
    int co = blockIdx.x, sub = blockIdx.y;
    int t = threadIdx.x;

    // attention for all 8 b of this sub (first 32 lanes of wave 0)
    if (t < 32) {
        int b = t >> 2, k = t & 3;
        const float* pp = plog + ((size_t)(b * 4 + sub) * 4 + k) * 64;
        float acc = 0.f;
        #pragma unroll 8
        for (int yy = 0; yy < 64; ++yy) acc += pp[yy];
        float logit = acc * (1.0f / 4096.0f) + attn_b[k];
        float m = fmaxf(logit, __shfl_xor(logit, 1));
        m = fmaxf(m, __shfl_xor(m, 2));
        float e = expf(logit - m);
        float s = e + __shfl_xor(e, 1);
        s += __shfl_xor(s, 2);
        satt[b][k] = e / s;
    }
    // stage wt[k][sub][co][:][:] for k=0..3 (contiguous 576-f32 runs, coalesced)
    for (int e = t; e < 2304; e += 256) {
        int k = e / 576, r = e - k * 576;
        sLw[k][r] = wt[((size_t)(k * 4 + sub) * 64 + co) * 576 + r];
    }
    __syncthreads();
    // produce all 8 b: 18 outputs/thread, 128B-coalesced bf16 writes.
    #pragma unroll
    for (int j = 0; j < 18; ++j) {
        int idx = j * 256 + t;
        int b = idx / 576;
        int r = idx - b * 576;
        int tap = r >> 6, ci = r & 63;
        int wi = ci * 9 + tap;
        float v = satt[b][0] * sLw[0][wi] + satt[b][1] * sLw[1][wi]
                + satt[b][2] * sLw[2][wi] + satt[b][3] * sLw[3][wi];
        wmix[((size_t)(b * 4 + sub) * 9 + tap) * 4096 + co * 64 + ci] = bf16bits(v);
    }
}

// ---------------------------------------------------------------------------
// K3: fused MFMA conv (all 4 subbands) + Haar IDWT epilogue -> f32 out.
// grid (4 cg, 16 tiles, 8 b) = 512 blocks, 256 threads (4 waves).
// Register-staged pipeline: global loads for stage s+1 issue before the MFMA
// compute of stage s; LDS commit happens after the barrier. Removes the
// per-stage vmcnt(0)+barrier global-latency drain.
// ---------------------------------------------------------------------------
__global__ __launch_bounds__(256, 2)
void conv_idwt_kernel(const unsigned short* __restrict__ feats,
                      const unsigned short* __restrict__ wmix,
                      float* __restrict__ out) {
    __shared__ uint4 sA[2592];         // [2 sub][18 py][18 px][4 kg]
    __shared__ uint4 sW[1152];         // [2 sub][9 tap][16 co][4 kg]
    int cg = blockIdx.x, tile = blockIdx.y, b = blockIdx.z;
    int y0 = (tile >> 2) * 16, x0 = (tile & 3) * 16;
    int t = threadIdx.x, w = t >> 6, l = t & 63;
    int l16 = l & 15, kg = l >> 4;
    int w4 = w * 4;
    const uint4* fchb = (const uint4*)feats + (size_t)b * 131072;  // [sub][y][x][ck]
    const uint4* wchb = (const uint4*)wmix + (size_t)b * 18432;    // [sub][tap][co][ck]

    f32x4 acc[4][4];                   // [sub][r]
    #pragma unroll
    for (int s = 0; s < 4; ++s)
        #pragma unroll
        for (int r = 0; r < 4; ++r)
            acc[s][r] = (f32x4){0.f, 0.f, 0.f, 0.f};

    // precomputed per-thread staging decode (invariant across stages)
    int adec_py[11], adec_gx[11], adec_off[11];    // A: plane-local info
    int adec_s2[11];
    bool a_ok[11];
    #pragma unroll
    for (int i = 0; i < 11; ++i) {
        int e = t + i * 256;
        if (e < 2592) {
            int s2 = e / 1296, rr = e - s2 * 1296;
            int py = rr / 72, r2 = rr - py * 72, px = r2 >> 2, g = r2 & 3;
            int gy = y0 - 1 + py, gx = x0 - 1 + px;
            adec_s2[i] = s2;
            a_ok[i] = ((unsigned)gy < 64u) && ((unsigned)gx < 64u);
            adec_off[i] = (gy * 64 + gx) * 8 + g;  // + ck8 at use
            adec_py[i] = 0; adec_gx[i] = 0;
        } else { a_ok[i] = false; adec_s2[i] = 0; adec_off[i] = 0; }
    }
    int wdec_s2[5], wdec_off[5];
    #pragma unroll
    for (int i = 0; i < 5; ++i) {
        int e = t + i * 256;
        if (e < 1152) {
            int s2 = e / 576, r = e - s2 * 576;
            int tap = r >> 6, co = (r >> 2) & 15, g = r & 3;
            wdec_s2[i] = s2;
            wdec_off[i] = tap * 512 + (cg * 16 + co) * 8 + g;  // + ck8 at use
        } else { wdec_s2[i] = 0; wdec_off[i] = -1; }
    }

    uint4 ra[11], rw[5];
    // ---- load stage 0 into registers ----
    {
        const int sp = 0, ck8 = 0;
        #pragma unroll
        for (int i = 0; i < 11; ++i) {
            uint4 v = make_uint4(0u, 0u, 0u, 0u);
            if (a_ok[i])
                v = fchb[(size_t)(sp * 2 + adec_s2[i]) * 32768 + adec_off[i] + ck8];
            ra[i] = v;
        }
        #pragma unroll
        for (int i = 0; i < 5; ++i)
            if (wdec_off[i] >= 0)
                rw[i] = wchb[(size_t)(sp * 2 + wdec_s2[i]) * 4608 + wdec_off[i] + ck8];
    }

    #pragma unroll
    for (int stg = 0; stg < 4; ++stg) {
        __syncthreads();               // LDS free (previous stage's readers done)
        // commit registers -> LDS
        #pragma unroll
        for (int i = 0; i < 11; ++i) { int e = t + i * 256; if (e < 2592) sA[e] = ra[i]; }
        #pragma unroll
        for (int i = 0; i < 5; ++i)  { int e = t + i * 256; if (e < 1152) sW[e] = rw[i]; }
        __syncthreads();
        // prefetch next stage into registers (overlaps with compute below)
        if (stg < 3) {
            const int sp = (stg + 1) >> 1, ck8 = ((stg + 1) & 1) * 4;
            #pragma unroll
            for (int i = 0; i < 11; ++i) {
                uint4 v = make_uint4(0u, 0u, 0u, 0u);
                if (a_ok[i])
                    v = fchb[(size_t)(sp * 2 + adec_s2[i]) * 32768 + adec_off[i] + ck8];
                ra[i] = v;
            }
            #pragma unroll
            for (int i = 0; i < 5; ++i)
                if (wdec_off[i] >= 0)
                    rw[i] = wchb[(size_t)(sp * 2 + wdec_s2[i]) * 4608 + wdec_off[i] + ck8];
        }
        // compute this stage
        #pragma unroll
        for (int s2 = 0; s2 < 2; ++s2) {
            const int sidx = (stg >> 1) * 2 + s2;
            int abase = s2 * 1296;
            // sliding-window A-frag cache over dy
            uint4 af[4][3];
            #pragma unroll
            for (int i = 0; i < 4; ++i)
                #pragma unroll
                for (int dx = 0; dx < 3; ++dx)
                    af[i][dx] = sA[abase + ((w4 + i) * 18 + l16 + dx) * 4 + kg];
            #pragma unroll
            for (int dy = 0; dy < 3; ++dy) {
                if (dy > 0) {
                    #pragma unroll
                    for (int i = 0; i < 3; ++i)
                        #pragma unroll
                        for (int dx = 0; dx < 3; ++dx)
                            af[i][dx] = af[i + 1][dx];
                    #pragma unroll
                    for (int dx = 0; dx < 3; ++dx)
                        af[3][dx] = sA[abase + ((w4 + dy + 3) * 18 + l16 + dx) * 4 + kg];
                }
                #pragma unroll
                for (int dx = 0; dx < 3; ++dx) {
                    uint4 bw = sW[s2 * 576 + (dy * 3 + dx) * 64 + l16 * 4 + kg];
                    bf16x8 bfr = as_bf16x8(bw);
                    #pragma unroll
                    for (int r = 0; r < 4; ++r)
                        acc[sidx][r] = __builtin_amdgcn_mfma_f32_16x16x32_bf16(
                            as_bf16x8(af[r][dx]), bfr, acc[sidx][r], 0, 0, 0);
                }
            }
        }
    }
    // IDWT epilogue: lane holds 4 sub-values at (y,x,co); write f32x4 pairs.
    int co = cg * 16 + l16;
    #pragma unroll
    for (int r = 0; r < 4; ++r) {
        int ys = y0 + w4 + r;
        float* orow = out + ((size_t)(b * 64 + co) * 128 + 2 * ys) * 128 + 2 * x0 + 8 * kg;
        float av[4], bv[4], cv[4], dv[4];
        #pragma unroll
        for (int j = 0; j < 4; ++j) {
            float ll = acc[0][r][j], h0 = acc[1][r][j];
            float h1 = acc[2][r][j], hh = acc[3][r][j];
            av[j] = (ll + h0 + h1 + hh) * 0.5f;
            bv[j] = (ll + h0 - h1 - hh) * 0.5f;
            cv[j] = (ll - h0 + h1 - hh) * 0.5f;
            dv[j] = (ll - h0 - h1 + hh) * 0.5f;
        }
        *(float4*)(orow)           = make_float4(av[0], bv[0], av[1], bv[1]);
        *(float4*)(orow + 4)       = make_float4(av[2], bv[2], av[3], bv[3]);
        *(float4*)(orow + 128)     = make_float4(cv[0], dv[0], cv[1], dv[1]);
        *(float4*)(orow + 132)     = make_float4(cv[2], dv[2], cv[3], dv[3]);
    }
}

// ---------------------------------------------------------------------------
extern "C" void kernel_launch(void* const* d_in, const int* in_sizes, int n_in,
                              void* d_out, int out_size, void* d_ws, size_t ws_size,
                              hipStream_t stream) {
    const float* x  = (const float*)d_in[0];
    const float* wt = (const float*)d_in[1];
    const float* aw = (const float*)d_in[2];
    const float* ab = (const float*)d_in[3];
    float* out = (float*)d_out;
    char* ws = (char*)d_ws;

    float* plog              = (float*)ws;                         // 32,768 B
    unsigned short* feats    = (unsigned short*)(ws + 32768);      // 16,777,216 B
    unsigned short* wmix     = (unsigned short*)(ws + 32768 + 16777216); // 2,359,296 B

    hipLaunchKernelGGL(dwt_kernel, dim3(64, 8), dim3(256), 0, stream, x, aw, feats, plog);
    hipLaunchKernelGGL(mix_kernel, dim3(64, 4), dim3(256), 0, stream, wt, ab, plog, wmix);
    hipLaunchKernelGGL(conv_idwt_kernel, dim3(4, 16, 8), dim3(256), 0, stream,
                       feats, wmix, out);
}

// Round 6
// 123.666 us; speedup vs baseline: 1.0890x; 1.0890x over previous
//
#include <hip/hip_runtime.h>
#include <hip/hip_bf16.h>
#include <math.h>

// Shapes: x(8,64,128,128) f32; wt(4,4,64,64,3,3) f32; attn_w(4,64); attn_b(4)
// Subband space: 64x64, 4 subbands, 64 cin, 64 cout.

typedef __bf16 bf16x8 __attribute__((ext_vector_type(8)));
typedef float f32x4 __attribute__((ext_vector_type(4)));

__device__ __forceinline__ bf16x8 as_bf16x8(uint4 u) {
    union { uint4 a; bf16x8 b; } c; c.a = u; return c.b;
}
__device__ __forceinline__ unsigned short bf16bits(float f) {
    __hip_bfloat16 h = __float2bfloat16(f);
    union { __hip_bfloat16 h; unsigned short u; } c; c.h = h; return c.u;
}

// ---------------------------------------------------------------------------
// K1: Haar DWT -> bf16 feats[b][sub][y][x][c] + per-y partial logits
//     plog[b][sub][k][y] (no atomics, no zero-init needed).
// grid (64 y, 8 b), 256 threads.
// ---------------------------------------------------------------------------
__global__ __launch_bounds__(256)
void dwt_kernel(const float* __restrict__ x, const float* __restrict__ attn_w,
                unsigned short* __restrict__ feats, float* __restrict__ plog) {
    __shared__ uint4 sT[2304];                     // 4 sub * 64 x * 9 chunks (72 bf16)
    __shared__ float sred[64][4];                  // [c][sub] per-block channel sums
    unsigned short* sTu = (unsigned short*)sT;
    int y = blockIdx.x, b = blockIdx.y;
    int t = threadIdx.x;
    int c = t >> 2, q = t & 3;

    const float4* r0 = (const float4*)x + ((size_t)(b * 64 + c) * 128 + 2 * y) * 32;
    const float4* r1 = r0 + 32;                    // next image row

    float s0 = 0.f, s1 = 0.f, s2 = 0.f, s3 = 0.f;
    #pragma unroll
    for (int i = 0; i < 8; ++i) {
        int f = i * 4 + q;                         // quad covers 4 consecutive float4
        float4 p = r0[f], qq = r1[f];
        int xo = 2 * f;
        {
            float a = p.x, bb = p.y, cc = qq.x, dd = qq.y;
            float ll = (a + bb + cc + dd) * 0.5f, h0 = (a + bb - cc - dd) * 0.5f;
            float h1 = (a - bb + cc - dd) * 0.5f, hh = (a - bb - cc + dd) * 0.5f;
            s0 += ll; s1 += h0; s2 += h1; s3 += hh;
            sTu[0 * 4608 + xo * 72 + c] = bf16bits(ll);
            sTu[1 * 4608 + xo * 72 + c] = bf16bits(h0);
            sTu[2 * 4608 + xo * 72 + c] = bf16bits(h1);
            sTu[3 * 4608 + xo * 72 + c] = bf16bits(hh);
        }
        {
            float a = p.z, bb = p.w, cc = qq.z, dd = qq.w;
            float ll = (a + bb + cc + dd) * 0.5f, h0 = (a + bb - cc - dd) * 0.5f;
            float h1 = (a - bb + cc - dd) * 0.5f, hh = (a - bb - cc + dd) * 0.5f;
            s0 += ll; s1 += h0; s2 += h1; s3 += hh;
            sTu[0 * 4608 + (xo + 1) * 72 + c] = bf16bits(ll);
            sTu[1 * 4608 + (xo + 1) * 72 + c] = bf16bits(h0);
            sTu[2 * 4608 + (xo + 1) * 72 + c] = bf16bits(h1);
            sTu[3 * 4608 + (xo + 1) * 72 + c] = bf16bits(hh);
        }
    }
    // reduce over q (4 consecutive lanes share c) -> sred[c][sub]
    s0 += __shfl_xor(s0, 1); s0 += __shfl_xor(s0, 2);
    s1 += __shfl_xor(s1, 1); s1 += __shfl_xor(s1, 2);
    s2 += __shfl_xor(s2, 1); s2 += __shfl_xor(s2, 2);
    s3 += __shfl_xor(s3, 1); s3 += __shfl_xor(s3, 2);
    if (q == 0) { sred[c][0] = s0; sred[c][1] = s1; sred[c][2] = s2; sred[c][3] = s3; }
    __syncthreads();
    // per-y partial logits (16 threads; others proceed to feats write)
    if (t < 16) {
        int sub = t >> 2, k = t & 3;
        float acc = 0.f;
        #pragma unroll 8
        for (int cc = 0; cc < 64; ++cc)
            acc += attn_w[k * 64 + cc] * sred[cc][sub];
        plog[((size_t)(b * 4 + sub) * 4 + k) * 64 + y] = acc;
    }
    // coalesced channel-last global writes (16B/lane)
    uint4* fch = (uint4*)feats;
    for (int e = t; e < 2048; e += 256) {
        int s = e >> 9, xx = (e >> 3) & 63, ck = e & 7;
        fch[(size_t)((b * 4 + s) * 64 + y) * 512 + xx * 8 + ck] = sT[s * 576 + xx * 9 + ck];
    }
}

// ---------------------------------------------------------------------------
// K2: attention (from plog) + kernel mixing -> bf16 wmix[b][sub][tap][co][ci]
// grid (64 co, 4 sub), 256 threads.
// ---------------------------------------------------------------------------
__global__ __launch_bounds__(256)
void mix_kernel(const float* __restrict__ wt, const float* __restrict__ attn_b,
                const float* __restrict__ plog, unsigned short* __restrict__ wmix) {
    __shared__ float sLw[4][576];       // [k][ci*9+tap]
    __shared__ float satt[8][4];        // [b][k]
    int co = blockIdx.x, sub = blockIdx.y;
    int t = threadIdx.x;

    // attention for all 8 b of this sub (first 32 lanes of wave 0)
    if (t < 32) {
        int b = t >> 2, k = t & 3;
        const float* pp = plog + ((size_t)(b * 4 + sub) * 4 + k) * 64;
        float acc = 0.f;
        #pragma unroll 8
        for (int yy = 0; yy < 64; ++yy) acc += pp[yy];
        float logit = acc * (1.0f / 4096.0f) + attn_b[k];
        float m = fmaxf(logit, __shfl_xor(logit, 1));
        m = fmaxf(m, __shfl_xor(m, 2));
        float e = expf(logit - m);
        float s = e + __shfl_xor(e, 1);
        s += __shfl_xor(s, 2);
        satt[b][k] = e / s;
    }
    // stage wt[k][sub][co][:][:] for k=0..3 (contiguous 576-f32 runs, coalesced)
    for (int e = t; e < 2304; e += 256) {
        int k = e / 576, r = e - k * 576;
        sLw[k][r] = wt[((size_t)(k * 4 + sub) * 64 + co) * 576 + r];
    }
    __syncthreads();
    // produce all 8 b: 18 outputs/thread, 128B-coalesced bf16 writes.
    #pragma unroll
    for (int j = 0; j < 18; ++j) {
        int idx = j * 256 + t;
        int b = idx / 576;
        int r = idx - b * 576;
        int tap = r >> 6, ci = r & 63;
        int wi = ci * 9 + tap;
        float v = satt[b][0] * sLw[0][wi] + satt[b][1] * sLw[1][wi]
                + satt[b][2] * sLw[2][wi] + satt[b][3] * sLw[3][wi];
        wmix[((size_t)(b * 4 + sub) * 9 + tap) * 4096 + co * 64 + ci] = bf16bits(v);
    }
}

// ---------------------------------------------------------------------------
// K3: MFMA implicit-GEMM 3x3 conv per (b,sub), 16x16 px x 32 couts per block.
// grid (32 = tile*2cg, 4 sub, 8 b) = 1024 blocks, 256 threads (4 waves).
// LDS 39.2 KB -> 4 blocks/CU, 4 waves/SIMD. No dynamic-indexed register
// arrays (avoids the round-5 LDS spill). Sliding-window A-frag cache.
// ---------------------------------------------------------------------------
__global__ __launch_bounds__(256, 4)
void conv_kernel(const unsigned short* __restrict__ feats,
                 const unsigned short* __restrict__ wmix,
                 unsigned short* __restrict__ conv_out) {
    __shared__ uint4 sA[1296];         // [18 py][18 px][4 g] : 18x18 halo x 32 ci
    __shared__ uint4 sW[1152];         // [9 tap][32 co][4 g] : 32 ci
    int bx = blockIdx.x;
    int tile = bx & 15, cg = bx >> 4;  // cg 0..1 (co half)
    int sub = blockIdx.y, b = blockIdx.z;
    int y0 = (tile >> 2) * 16, x0 = (tile & 3) * 16;
    int t = threadIdx.x, w = t >> 6, l = t & 63;
    int l16 = l & 15, kg = l >> 4;
    int w4 = w * 4;
    const uint4* fch = (const uint4*)feats + (size_t)(b * 4 + sub) * 32768;
    const uint4* wch = (const uint4*)wmix + (size_t)(b * 4 + sub) * 4608;

    f32x4 acc[4][2];                   // [r][nn]
    #pragma unroll
    for (int r = 0; r < 4; ++r) {
        acc[r][0] = (f32x4){0.f, 0.f, 0.f, 0.f};
        acc[r][1] = (f32x4){0.f, 0.f, 0.f, 0.f};
    }

    #pragma unroll
    for (int ck8 = 0; ck8 < 8; ck8 += 4) {   // two 32-ci chunks
        __syncthreads();
        // stage A halo (zero-fill OOB)
        for (int e = t; e < 1296; e += 256) {
            int py = e / 72, rr = e - py * 72, px = rr >> 2, g = rr & 3;
            int gy = y0 - 1 + py, gx = x0 - 1 + px;
            uint4 v = make_uint4(0u, 0u, 0u, 0u);
            if ((unsigned)gy < 64u && (unsigned)gx < 64u)
                v = fch[(gy * 64 + gx) * 8 + ck8 + g];
            sA[e] = v;
        }
        // stage W: 9 taps x 32 co (this cg half) x 32 ci
        for (int e = t; e < 1152; e += 256) {
            int tap = e >> 7, rr = e & 127, co = rr >> 2, g = rr & 3;
            sW[e] = wch[tap * 512 + (cg * 32 + co) * 8 + ck8 + g];
        }
        __syncthreads();
        // sliding-window A-frag cache over dy
        uint4 af[4][3];
        #pragma unroll
        for (int i = 0; i < 4; ++i)
            #pragma unroll
            for (int dx = 0; dx < 3; ++dx)
                af[i][dx] = sA[((w4 + i) * 18 + l16 + dx) * 4 + kg];
        #pragma unroll
        for (int dy = 0; dy < 3; ++dy) {
            if (dy > 0) {
                #pragma unroll
                for (int i = 0; i < 3; ++i)
                    #pragma unroll
                    for (int dx = 0; dx < 3; ++dx)
                        af[i][dx] = af[i + 1][dx];
                #pragma unroll
                for (int dx = 0; dx < 3; ++dx)
                    af[3][dx] = sA[((w4 + dy + 3) * 18 + l16 + dx) * 4 + kg];
            }
            #pragma unroll
            for (int dx = 0; dx < 3; ++dx) {
                int tap = dy * 3 + dx;
                bf16x8 bw0 = as_bf16x8(sW[tap * 128 + l16 * 4 + kg]);
                bf16x8 bw1 = as_bf16x8(sW[tap * 128 + (16 + l16) * 4 + kg]);
                #pragma unroll
                for (int r = 0; r < 4; ++r) {
                    acc[r][0] = __builtin_amdgcn_mfma_f32_16x16x32_bf16(
                        as_bf16x8(af[r][dx]), bw0, acc[r][0], 0, 0, 0);
                    acc[r][1] = __builtin_amdgcn_mfma_f32_16x16x32_bf16(
                        as_bf16x8(af[r][dx]), bw1, acc[r][1], 0, 0, 0);
                }
            }
        }
    }
    // epilogue: D row=(lane>>4)*4+reg = x offset, col=lane&15 = co (within 16)
    size_t obase = (size_t)(b * 4 + sub) * 262144;
    #pragma unroll
    for (int r = 0; r < 4; ++r) {
        int yy = y0 + w4 + r;
        #pragma unroll
        for (int nn = 0; nn < 2; ++nn) {
            int co = cg * 32 + nn * 16 + l16;
            #pragma unroll
            for (int j = 0; j < 4; ++j) {
                int xx = x0 + kg * 4 + j;
                conv_out[obase + ((size_t)yy * 64 + xx) * 64 + co] = bf16bits(acc[r][nn][j]);
            }
        }
    }
}

// ---------------------------------------------------------------------------
// K4: Haar IDWT: conv_out[b][sub][y][x][co] bf16 -> out[b][co][Y][X] f32
// grid (64 y, 8 b), 256 threads. LDS transpose.
// ---------------------------------------------------------------------------
__global__ __launch_bounds__(256)
void idwt_kernel(const unsigned short* __restrict__ conv_out,
                 float* __restrict__ out) {
    __shared__ uint4 sT[2304];         // [sub][x][9 chunks] (8 used = 64 c)
    int y = blockIdx.x, b = blockIdx.y;
    int t = threadIdx.x;
    const uint4* cch = (const uint4*)conv_out;
    for (int e = t; e < 2048; e += 256) {
        int s = e >> 9, xx = (e >> 3) & 63, ck = e & 7;
        sT[s * 576 + xx * 9 + ck] = cch[(size_t)(b * 4 + s) * 32768 + y * 512 + xx * 8 + ck];
    }
    __syncthreads();
    int xx = t & 63, cw = t >> 6;
    #pragma unroll
    for (int half = 0; half < 2; ++half) {
        int ckk = half * 4 + cw;       // c chunk 0..7
        bf16x8 v0 = as_bf16x8(sT[0 * 576 + xx * 9 + ckk]);
        bf16x8 v1 = as_bf16x8(sT[1 * 576 + xx * 9 + ckk]);
        bf16x8 v2 = as_bf16x8(sT[2 * 576 + xx * 9 + ckk]);
        bf16x8 v3 = as_bf16x8(sT[3 * 576 + xx * 9 + ckk]);
        #pragma unroll
        for (int j = 0; j < 8; ++j) {
            int c = ckk * 8 + j;
            float ll = (float)v0[j], h0 = (float)v1[j];
            float h1 = (float)v2[j], hh = (float)v3[j];
            float a = (ll + h0 + h1 + hh) * 0.5f;
            float bb = (ll + h0 - h1 - hh) * 0.5f;
            float cc = (ll - h0 + h1 - hh) * 0.5f;
            float dd = (ll - h0 - h1 + hh) * 0.5f;
            float2* o0 = (float2*)out + ((size_t)(b * 64 + c) * 128 + 2 * y) * 64 + xx;
            o0[0]  = make_float2(a, bb);
            o0[64] = make_float2(cc, dd);
        }
    }
}

// ---------------------------------------------------------------------------
extern "C" void kernel_launch(void* const* d_in, const int* in_sizes, int n_in,
                              void* d_out, int out_size, void* d_ws, size_t ws_size,
                              hipStream_t stream) {
    const float* x  = (const float*)d_in[0];
    const float* wt = (const float*)d_in[1];
    const float* aw = (const float*)d_in[2];
    const float* ab = (const float*)d_in[3];
    float* out = (float*)d_out;
    char* ws = (char*)d_ws;

    float* plog              = (float*)ws;                         // 32,768 B
    unsigned short* feats    = (unsigned short*)(ws + 32768);      // 16,777,216 B
    unsigned short* wmix     = (unsigned short*)(ws + 32768 + 16777216);        // 2,359,296 B
    unsigned short* conv_out = (unsigned short*)(ws + 32768 + 16777216 + 2359296); // 16,777,216 B

    hipLaunchKernelGGL(dwt_kernel, dim3(64, 8), dim3(256), 0, stream, x, aw, feats, plog);
    hipLaunchKernelGGL(mix_kernel, dim3(64, 4), dim3(256), 0, stream, wt, ab, plog, wmix);
    hipLaunchKernelGGL(conv_kernel, dim3(32, 4, 8), dim3(256), 0, stream,
                       feats, wmix, conv_out);
    hipLaunchKernelGGL(idwt_kernel, dim3(64, 8), dim3(256), 0, stream, conv_out, out);
}

// Round 7
// 122.592 us; speedup vs baseline: 1.0986x; 1.0088x over previous
//
#include <hip/hip_runtime.h>
#include <hip/hip_bf16.h>
#include <math.h>

// Shapes: x(8,64,128,128) f32; wt(4,4,64,64,3,3) f32; attn_w(4,64); attn_b(4)
// Subband space: 64x64, 4 subbands, 64 cin, 64 cout.
// feats layout: [b][sub][66][66][64c] bf16, zero border ring (pad=1).

typedef __bf16 bf16x8 __attribute__((ext_vector_type(8)));
typedef float f32x4 __attribute__((ext_vector_type(4)));

__device__ __forceinline__ bf16x8 as_bf16x8(uint4 u) {
    union { uint4 a; bf16x8 b; } c; c.a = u; return c.b;
}
__device__ __forceinline__ unsigned short bf16bits(float f) {
    __hip_bfloat16 h = __float2bfloat16(f);
    union { __hip_bfloat16 h; unsigned short u; } c; c.h = h; return c.u;
}
// async 16B global -> LDS (DMA; LDS dest = wave-uniform base + lane*16)
__device__ __forceinline__ void gload_lds16(const uint4* g, uint4* l) {
    __builtin_amdgcn_global_load_lds(
        (const __attribute__((address_space(1))) unsigned int*)g,
        (__attribute__((address_space(3))) unsigned int*)l, 16, 0, 0);
}

#define FPLANE 34848   // 66*66*8 uint4 per (b,sub) plane
#define FROW   528     // 66*8

// ---------------------------------------------------------------------------
// K1: Haar DWT -> bf16 feats (padded, zero ring) + per-y partial logits
// grid (64 y, 8 b), 256 threads.
// ---------------------------------------------------------------------------
__global__ __launch_bounds__(256)
void dwt_kernel(const float* __restrict__ x, const float* __restrict__ attn_w,
                unsigned short* __restrict__ feats, float* __restrict__ plog) {
    __shared__ uint4 sT[2304];                     // 4 sub * 64 x * 9 chunks (72 bf16)
    __shared__ float sred[64][4];                  // [c][sub]
    unsigned short* sTu = (unsigned short*)sT;
    int y = blockIdx.x, b = blockIdx.y;
    int t = threadIdx.x;
    int c = t >> 2, q = t & 3;

    const float4* r0 = (const float4*)x + ((size_t)(b * 64 + c) * 128 + 2 * y) * 32;
    const float4* r1 = r0 + 32;

    float s0 = 0.f, s1 = 0.f, s2 = 0.f, s3 = 0.f;
    #pragma unroll
    for (int i = 0; i < 8; ++i) {
        int f = i * 4 + q;                         // quad covers 64B contiguous
        float4 p = r0[f], qq = r1[f];
        int xo = 2 * f;
        {
            float a = p.x, bb = p.y, cc = qq.x, dd = qq.y;
            float ll = (a + bb + cc + dd) * 0.5f, h0 = (a + bb - cc - dd) * 0.5f;
            float h1 = (a - bb + cc - dd) * 0.5f, hh = (a - bb - cc + dd) * 0.5f;
            s0 += ll; s1 += h0; s2 += h1; s3 += hh;
            sTu[0 * 4608 + xo * 72 + c] = bf16bits(ll);
            sTu[1 * 4608 + xo * 72 + c] = bf16bits(h0);
            sTu[2 * 4608 + xo * 72 + c] = bf16bits(h1);
            sTu[3 * 4608 + xo * 72 + c] = bf16bits(hh);
        }
        {
            float a = p.z, bb = p.w, cc = qq.z, dd = qq.w;
            float ll = (a + bb + cc + dd) * 0.5f, h0 = (a + bb - cc - dd) * 0.5f;
            float h1 = (a - bb + cc - dd) * 0.5f, hh = (a - bb - cc + dd) * 0.5f;
            s0 += ll; s1 += h0; s2 += h1; s3 += hh;
            sTu[0 * 4608 + (xo + 1) * 72 + c] = bf16bits(ll);
            sTu[1 * 4608 + (xo + 1) * 72 + c] = bf16bits(h0);
            sTu[2 * 4608 + (xo + 1) * 72 + c] = bf16bits(h1);
            sTu[3 * 4608 + (xo + 1) * 72 + c] = bf16bits(hh);
        }
    }
    s0 += __shfl_xor(s0, 1); s0 += __shfl_xor(s0, 2);
    s1 += __shfl_xor(s1, 1); s1 += __shfl_xor(s1, 2);
    s2 += __shfl_xor(s2, 1); s2 += __shfl_xor(s2, 2);
    s3 += __shfl_xor(s3, 1); s3 += __shfl_xor(s3, 2);
    if (q == 0) { sred[c][0] = s0; sred[c][1] = s1; sred[c][2] = s2; sred[c][3] = s3; }
    __syncthreads();
    if (t < 16) {
        int sub = t >> 2, k = t & 3;
        float acc = 0.f;
        #pragma unroll 8
        for (int cc = 0; cc < 64; ++cc)
            acc += attn_w[k * 64 + cc] * sred[cc][sub];
        plog[((size_t)(b * 4 + sub) * 4 + k) * 64 + y] = acc;
    }
    // padded channel-last writes: row y+1 of each plane, zero side borders
    uint4* fpad = (uint4*)feats;
    const uint4 zz = make_uint4(0u, 0u, 0u, 0u);
    for (int e = t; e < 2112; e += 256) {
        int s = e / 528, r = e - s * 528;
        int px = r >> 3, ck = r & 7;
        uint4 v = zz;
        if (px >= 1 && px <= 64) v = sT[s * 576 + (px - 1) * 9 + ck];
        fpad[((size_t)(b * 4 + s) * 66 + (y + 1)) * FROW + r] = v;
    }
    if (y == 0) {
        for (int e = t; e < 2112; e += 256) {
            int s = e / 528, r = e - s * 528;
            fpad[(size_t)(b * 4 + s) * 66 * FROW + r] = zz;
        }
    } else if (y == 63) {
        for (int e = t; e < 2112; e += 256) {
            int s = e / 528, r = e - s * 528;
            fpad[((size_t)(b * 4 + s) * 66 + 65) * FROW + r] = zz;
        }
    }
}

// ---------------------------------------------------------------------------
// K2: attention (from plog) + kernel mixing -> bf16 wmix[b][sub][tap][co][ci]
// grid (64 co, 4 sub), 256 threads.
// ---------------------------------------------------------------------------
__global__ __launch_bounds__(256)
void mix_kernel(const float* __restrict__ wt, const float* __restrict__ attn_b,
                const float* __restrict__ plog, unsigned short* __restrict__ wmix) {
    __shared__ float sLw[4][576];       // [k][ci*9+tap]
    __shared__ float satt[8][4];        // [b][k]
    int co = blockIdx.x, sub = blockIdx.y;
    int t = threadIdx.x;

    if (t < 32) {
        int b = t >> 2, k = t & 3;
        const float* pp = plog + ((size_t)(b * 4 + sub) * 4 + k) * 64;
        float acc = 0.f;
        #pragma unroll 8
        for (int yy = 0; yy < 64; ++yy) acc += pp[yy];
        float logit = acc * (1.0f / 4096.0f) + attn_b[k];
        float m = fmaxf(logit, __shfl_xor(logit, 1));
        m = fmaxf(m, __shfl_xor(m, 2));
        float e = expf(logit - m);
        float s = e + __shfl_xor(e, 1);
        s += __shfl_xor(s, 2);
        satt[b][k] = e / s;
    }
    for (int e = t; e < 2304; e += 256) {
        int k = e / 576, r = e - k * 576;
        sLw[k][r] = wt[((size_t)(k * 4 + sub) * 64 + co) * 576 + r];
    }
    __syncthreads();
    #pragma unroll
    for (int j = 0; j < 18; ++j) {
        int idx = j * 256 + t;
        int b = idx / 576;
        int r = idx - b * 576;
        int tap = r >> 6, ci = r & 63;
        int wi = ci * 9 + tap;
        float v = satt[b][0] * sLw[0][wi] + satt[b][1] * sLw[1][wi]
                + satt[b][2] * sLw[2][wi] + satt[b][3] * sLw[3][wi];
        wmix[((size_t)(b * 4 + sub) * 9 + tap) * 4096 + co * 64 + ci] = bf16bits(v);
    }
}

// ---------------------------------------------------------------------------
// K3: MFMA implicit-GEMM 3x3 conv per (b,sub), 16x16 px x 32 couts per block.
// grid (32 = tile*2cg, 4 sub, 8 b) = 1024 blocks, 256 threads (4 waves).
// Async global_load_lds (16B) staging, guard-free via padded feats.
// LDS 39.2 KB -> 4 blocks/CU.
// ---------------------------------------------------------------------------
__global__ __launch_bounds__(256, 4)
void conv_kernel(const unsigned short* __restrict__ feats,
                 const unsigned short* __restrict__ wmix,
                 unsigned short* __restrict__ conv_out) {
    __shared__ uint4 sA[1296];         // [18 py][18 px][4 g] : 18x18 halo x 32 ci
    __shared__ uint4 sW[1152];         // [9 tap][32 co][4 g] : 32 ci
    int bx = blockIdx.x;
    int tile = bx & 15, cg = bx >> 4;
    int sub = blockIdx.y, b = blockIdx.z;
    int y0 = (tile >> 2) * 16, x0 = (tile & 3) * 16;
    int t = threadIdx.x, w = t >> 6, l = t & 63;
    int l16 = l & 15, kg = l >> 4;
    int w4 = w * 4;
    const uint4* fp  = (const uint4*)feats + (size_t)(b * 4 + sub) * FPLANE;
    const uint4* wch = (const uint4*)wmix + (size_t)(b * 4 + sub) * 4608;

    f32x4 acc[4][2];
    #pragma unroll
    for (int r = 0; r < 4; ++r) {
        acc[r][0] = (f32x4){0.f, 0.f, 0.f, 0.f};
        acc[r][1] = (f32x4){0.f, 0.f, 0.f, 0.f};
    }

    #pragma unroll
    for (int ck8 = 0; ck8 < 8; ck8 += 4) {   // two 32-ci chunks
        __syncthreads();
        // A halo: padded coords (y0+py, x0+px), py/px 0..17 -- always in-bounds
        #pragma unroll
        for (int i = 0; i < 5; ++i) {
            int e = t + i * 256;               // < 1280
            int py = e / 72, rr = e - py * 72, px = rr >> 2, g = rr & 3;
            gload_lds16(fp + (size_t)((y0 + py) * 66 + x0 + px) * 8 + ck8 + g, &sA[e]);
        }
        if (t < 16) {                          // tail: e 1280..1295 (py=17)
            int e = 1280 + t;
            int rr = e - 1224, px = rr >> 2, g = rr & 3;
            sA[e] = fp[(size_t)((y0 + 17) * 66 + x0 + px) * 8 + ck8 + g];
        }
        // W: 9 taps x 32 co (this cg half) x 32 ci
        #pragma unroll
        for (int i = 0; i < 4; ++i) {
            int e = t + i * 256;
            int tap = e >> 7, rr = e & 127, co = rr >> 2, g = rr & 3;
            gload_lds16(wch + tap * 512 + (cg * 32 + co) * 8 + ck8 + g, &sW[e]);
        }
        if (t < 128) {                         // tail: waves 0,1 (wave-uniform)
            int e = 1024 + t;
            int tap = e >> 7, rr = e & 127, co = rr >> 2, g = rr & 3;
            gload_lds16(wch + tap * 512 + (cg * 32 + co) * 8 + ck8 + g, &sW[e]);
        }
        __syncthreads();
        // sliding-window A-frag cache over dy
        uint4 af[4][3];
        #pragma unroll
        for (int i = 0; i < 4; ++i)
            #pragma unroll
            for (int dx = 0; dx < 3; ++dx)
                af[i][dx] = sA[((w4 + i) * 18 + l16 + dx) * 4 + kg];
        #pragma unroll
        for (int dy = 0; dy < 3; ++dy) {
            if (dy > 0) {
                #pragma unroll
                for (int i = 0; i < 3; ++i)
                    #pragma unroll
                    for (int dx = 0; dx < 3; ++dx)
                        af[i][dx] = af[i + 1][dx];
                #pragma unroll
                for (int dx = 0; dx < 3; ++dx)
                    af[3][dx] = sA[((w4 + dy + 3) * 18 + l16 + dx) * 4 + kg];
            }
            #pragma unroll
            for (int dx = 0; dx < 3; ++dx) {
                int tap = dy * 3 + dx;
                bf16x8 bw0 = as_bf16x8(sW[tap * 128 + l16 * 4 + kg]);
                bf16x8 bw1 = as_bf16x8(sW[tap * 128 + (16 + l16) * 4 + kg]);
                #pragma unroll
                for (int r = 0; r < 4; ++r) {
                    acc[r][0] = __builtin_amdgcn_mfma_f32_16x16x32_bf16(
                        as_bf16x8(af[r][dx]), bw0, acc[r][0], 0, 0, 0);
                    acc[r][1] = __builtin_amdgcn_mfma_f32_16x16x32_bf16(
                        as_bf16x8(af[r][dx]), bw1, acc[r][1], 0, 0, 0);
                }
            }
        }
    }
    // epilogue: D row=(lane>>4)*4+reg = x offset, col=lane&15 = co (within 16)
    size_t obase = (size_t)(b * 4 + sub) * 262144;
    #pragma unroll
    for (int r = 0; r < 4; ++r) {
        int yy = y0 + w4 + r;
        #pragma unroll
        for (int nn = 0; nn < 2; ++nn) {
            int co = cg * 32 + nn * 16 + l16;
            #pragma unroll
            for (int j = 0; j < 4; ++j) {
                int xx = x0 + kg * 4 + j;
                conv_out[obase + ((size_t)yy * 64 + xx) * 64 + co] = bf16bits(acc[r][nn][j]);
            }
        }
    }
}

// ---------------------------------------------------------------------------
// K4: Haar IDWT: conv_out[b][sub][y][x][co] bf16 -> out[b][co][Y][X] f32
// grid (64 y, 8 b), 256 threads. LDS transpose.
// ---------------------------------------------------------------------------
__global__ __launch_bounds__(256)
void idwt_kernel(const unsigned short* __restrict__ conv_out,
                 float* __restrict__ out) {
    __shared__ uint4 sT[2304];
    int y = blockIdx.x, b = blockIdx.y;
    int t = threadIdx.x;
    const uint4* cch = (const uint4*)conv_out;
    for (int e = t; e < 2048; e += 256) {
        int s = e >> 9, xx = (e >> 3) & 63, ck = e & 7;
        sT[s * 576 + xx * 9 + ck] = cch[(size_t)(b * 4 + s) * 32768 + y * 512 + xx * 8 + ck];
    }
    __syncthreads();
    int xx = t & 63, cw = t >> 6;
    #pragma unroll
    for (int half = 0; half < 2; ++half) {
        int ckk = half * 4 + cw;
        bf16x8 v0 = as_bf16x8(sT[0 * 576 + xx * 9 + ckk]);
        bf16x8 v1 = as_bf16x8(sT[1 * 576 + xx * 9 + ckk]);
        bf16x8 v2 = as_bf16x8(sT[2 * 576 + xx * 9 + ckk]);
        bf16x8 v3 = as_bf16x8(sT[3 * 576 + xx * 9 + ckk]);
        #pragma unroll
        for (int j = 0; j < 8; ++j) {
            int c = ckk * 8 + j;
            float ll = (float)v0[j], h0 = (float)v1[j];
            float h1 = (float)v2[j], hh = (float)v3[j];
            float a = (ll + h0 + h1 + hh) * 0.5f;
            float bb = (ll + h0 - h1 - hh) * 0.5f;
            float cc = (ll - h0 + h1 - hh) * 0.5f;
            float dd = (ll - h0 - h1 + hh) * 0.5f;
            float2* o0 = (float2*)out + ((size_t)(b * 64 + c) * 128 + 2 * y) * 64 + xx;
            o0[0]  = make_float2(a, bb);
            o0[64] = make_float2(cc, dd);
        }
    }
}

// ---------------------------------------------------------------------------
extern "C" void kernel_launch(void* const* d_in, const int* in_sizes, int n_in,
                              void* d_out, int out_size, void* d_ws, size_t ws_size,
                              hipStream_t stream) {
    const float* x  = (const float*)d_in[0];
    const float* wt = (const float*)d_in[1];
    const float* aw = (const float*)d_in[2];
    const float* ab = (const float*)d_in[3];
    float* out = (float*)d_out;
    char* ws = (char*)d_ws;

    float* plog              = (float*)ws;                              // 32,768 B
    unsigned short* feats    = (unsigned short*)(ws + 32768);           // 17,842,176 B (padded)
    unsigned short* wmix     = (unsigned short*)(ws + 32768 + 17842176);            // 2,359,296 B
    unsigned short* conv_out = (unsigned short*)(ws + 32768 + 17842176 + 2359296);  // 16,777,216 B

    hipLaunchKernelGGL(dwt_kernel, dim3(64, 8), dim3(256), 0, stream, x, aw, feats, plog);
    hipLaunchKernelGGL(mix_kernel, dim3(64, 4), dim3(256), 0, stream, wt, ab, plog, wmix);
    hipLaunchKernelGGL(conv_kernel, dim3(32, 4, 8), dim3(256), 0, stream,
                       feats, wmix, conv_out);
    hipLaunchKernelGGL(idwt_kernel, dim3(64, 8), dim3(256), 0, stream, conv_out, out);
}